// Round 17
// baseline (257.637 us; speedup 1.0000x reference)
//
#include <hip/hip_runtime.h>

typedef unsigned char u8;
typedef float f32x4 __attribute__((ext_vector_type(4)));
typedef _Float16 f16x8 __attribute__((ext_vector_type(8)));

#define DIM 128
#define TM  256   // eval: points per block (two 128-pt halves reuse staged W2)

__device__ __forceinline__ float fast_tanh(float x) {
    // tanh(x) = 1 - 2/(exp2(2x*log2e)+1); exact +-1 saturation via inf->0
    float e = __builtin_amdgcn_exp2f(x * 2.885390081777927f);
    return 1.0f - 2.0f * __builtin_amdgcn_rcpf(e + 1.0f);
}
__device__ __forceinline__ float fast_sigmoid(float x) {
    float e = __builtin_amdgcn_exp2f(x * -1.4426950408889634f);
    return __builtin_amdgcn_rcpf(1.0f + e);
}

// ---- dense MLP eval of the 513x513 grid; also writes the 257-grid shadow ----
// (coarser grids are exact subsets: u=(j*2^s)/512 == j/(R_l-1), bit-identical)
// 4 waves/block, 32 points/wave (mf=2), W2^T fp16 in LDS staged ONCE per block,
// two 128-point halves evaluated sequentially. b2 folded into acc init.
__global__ __launch_bounds__(256, 4) void eval_q4(
    const float* __restrict__ W1, const float* __restrict__ b1,
    const float* __restrict__ W2, const float* __restrict__ b2,
    const float* __restrict__ W3, const float* __restrict__ b3,
    const float* __restrict__ bmin, const float* __restrict__ bmax,
    float* __restrict__ q4, float* __restrict__ q257)
{
    __shared__ __align__(16) _Float16 sW2T[DIM * DIM];   // 32 KB

    const int R = 513;
    const int N = R * R;                 // 263169
    const int tid = threadIdx.x;
    const int m0 = blockIdx.x * TM;

    #pragma unroll
    for (int s = 0; s < 8; ++s) {
        int chunk = s * 256 + tid;       // 0..2047
        int n = chunk & 127, ko = chunk >> 7;
        f16x8 v;
        #pragma unroll
        for (int qq = 0; qq < 8; ++qq)
            v[qq] = (_Float16)W2[(ko * 8 + qq) * DIM + n];   // coalesced over n
        int slot = ko ^ (n & 15);
        *(f16x8*)&sW2T[n * DIM + slot * 8] = v;
    }

    const int w = tid >> 6, lane = tid & 63;
    const int l15 = lane & 15, lg = lane >> 4;

    const float inv = 1.0f / 512.0f;     // exact
    const float bx0 = bmin[0], by0 = bmin[1];
    const float sx = bmax[0] - bx0, sy = bmax[1] - by0;

    __syncthreads();

    for (int half = 0; half < 2; ++half) {
        const int h0 = m0 + half * 128;
        float xs[2], ys[2];
        #pragma unroll
        for (int mf = 0; mf < 2; ++mf) {
            int pi = h0 + w * 32 + mf * 16 + l15;
            int pg = (pi < N) ? pi : N - 1;
            int gi = pg / R, gj = pg - gi * R;
            xs[mf] = bx0 + (float)gj * inv * sx;
            ys[mf] = by0 + (float)gi * inv * sy;
        }

        // acc init = b2[col]
        f32x4 acc[2][8];
        #pragma unroll
        for (int nf = 0; nf < 8; ++nf) {
            float b2v = b2[nf * 16 + l15];
            acc[0][nf] = (f32x4)(b2v);
            acc[1][nf] = (f32x4)(b2v);
        }

        #pragma unroll
        for (int kf = 0; kf < 4; ++kf) {
            const int kbase = kf * 32 + lg * 8;
            f16x8 bh[8];
            #pragma unroll
            for (int nf = 0; nf < 8; ++nf) {
                int c = nf * 16 + l15;
                int slot = (kf * 4 + lg) ^ l15;   // matches write swizzle
                bh[nf] = *(const f16x8*)&sW2T[c * DIM + slot * 8];
            }
            f32x4 wxa = *(const f32x4*)&W1[kbase];
            f32x4 wxb = *(const f32x4*)&W1[kbase + 4];
            f32x4 wya = *(const f32x4*)&W1[DIM + kbase];
            f32x4 wyb = *(const f32x4*)&W1[DIM + kbase + 4];
            f32x4 b1a = *(const f32x4*)&b1[kbase];
            f32x4 b1b = *(const f32x4*)&b1[kbase + 4];
            f16x8 ah[2];
            #pragma unroll
            for (int mf = 0; mf < 2; ++mf) {
                float x = xs[mf], y = ys[mf];
                #pragma unroll
                for (int qq = 0; qq < 4; ++qq)
                    ah[mf][qq] = (_Float16)fast_tanh(fmaf(x, wxa[qq], fmaf(y, wya[qq], b1a[qq])));
                #pragma unroll
                for (int qq = 0; qq < 4; ++qq)
                    ah[mf][4 + qq] = (_Float16)fast_tanh(fmaf(x, wxb[qq], fmaf(y, wyb[qq], b1b[qq])));
            }
            #pragma unroll
            for (int nf = 0; nf < 8; ++nf)
                #pragma unroll
                for (int mf = 0; mf < 2; ++mf)
                    acc[mf][nf] = __builtin_amdgcn_mfma_f32_16x16x32_f16(ah[mf], bh[nf], acc[mf][nf], 0, 0, 0);
        }

        // epilogue; C/D: row = half*128 + w*32+mf*16+lg*4+rg, col = nf*16+l15
        float rs[2][4] = {{0,0,0,0},{0,0,0,0}};
        #pragma unroll
        for (int nf = 0; nf < 8; ++nf) {
            float w3v = W3[nf * 16 + l15];
            #pragma unroll
            for (int mf = 0; mf < 2; ++mf)
                #pragma unroll
                for (int rg = 0; rg < 4; ++rg)
                    rs[mf][rg] += fast_tanh(acc[mf][nf][rg]) * w3v;
        }
        #pragma unroll
        for (int mf = 0; mf < 2; ++mf)
            #pragma unroll
            for (int rg = 0; rg < 4; ++rg) {
                float v = rs[mf][rg];
                v += __shfl_xor(v, 1);
                v += __shfl_xor(v, 2);
                v += __shfl_xor(v, 4);
                v += __shfl_xor(v, 8);
                rs[mf][rg] = v;
            }
        if (l15 == 0) {
            float b3v = b3[0];
            #pragma unroll
            for (int mf = 0; mf < 2; ++mf)
                #pragma unroll
                for (int rg = 0; rg < 4; ++rg) {
                    int po = h0 + w * 32 + mf * 16 + lg * 4 + rg;
                    if (po < N) {
                        float val = fast_sigmoid(rs[mf][rg] + b3v);
                        q4[po] = val;
                        int gi = po / R, gj = po - gi * R;
                        if (((gi | gj) & 1) == 0)
                            q257[(gi >> 1) * 257 + (gj >> 1)] = val;  // bit-identical shadow
                    }
                }
        }
    }
}

// ---- one refinement level on a 24x24 window, one thread per cell ----
// Window core [4,20) is exact (influence radius of boundary+3 conflict iters
// is 4). Parents come from q257 (FIRST: 33-grid, stride 8) or the previous
// level's LDS patch; q comes from (qbuf,qpitch) at stride qs.
#define HWF 24
#define NTF 576
template<bool FIRST>
__device__ __forceinline__ void run_level(
    int c, int li, int lj, int oi0, int oj0, int R,
    const float* __restrict__ qbuf, int qpitch, int qs,
    const float* __restrict__ q257, int pOi, int pOj,
    const float* sOccP, const u8* sCalP,
    u8* sRaw, u8* sCfA, u8* sCfB,
    float& occR, bool& calR)
{
    const float BAL = 0.5f;
    const int fi = oi0 + li, fj = oj0 + lj;
    const bool inG = (fi >= 0 && fi < R && fj >= 0 && fj < R);
    float occ = 0.5f, qv = 0.5f;
    u8 rw = 0; bool cal = false;
    if (inG) qv = qbuf[(fi * qs) * qpitch + fj * qs];   // issued early, used late
    if (inG) {
        int ip = fi >> 1, jp = fj >> 1;
        int oi = fi & 1, oj = fj & 1;
        float tl = FIRST ? q257[(ip * 8) * 257 + jp * 8]
                         : sOccP[(ip - pOi) * HWF + (jp - pOj)];
        bool b;
        if (!oi && !oj) { occ = tl; b = false; }
        else if (oi && !oj) {
            float bl = FIRST ? q257[((ip + 1) * 8) * 257 + jp * 8]
                             : sOccP[(ip + 1 - pOi) * HWF + (jp - pOj)];
            occ = 0.5f * (tl + bl);
            b = (tl > BAL) != (bl > BAL);
        } else if (!oi && oj) {
            float tr = FIRST ? q257[(ip * 8) * 257 + (jp + 1) * 8]
                             : sOccP[(ip - pOi) * HWF + (jp + 1 - pOj)];
            occ = 0.5f * (tl + tr);
            b = (tl > BAL) != (tr > BAL);
        } else {
            float bl = FIRST ? q257[((ip + 1) * 8) * 257 + jp * 8]
                             : sOccP[(ip + 1 - pOi) * HWF + (jp - pOj)];
            float tr = FIRST ? q257[(ip * 8) * 257 + (jp + 1) * 8]
                             : sOccP[(ip - pOi) * HWF + (jp + 1 - pOj)];
            float br = FIRST ? q257[((ip + 1) * 8) * 257 + (jp + 1) * 8]
                             : sOccP[(ip + 1 - pOi) * HWF + (jp + 1 - pOj)];
            occ = 0.5f * (0.5f * (tl + bl) + 0.5f * (tr + br));  // exact _up2 order
            bool m0 = tl > BAL, m1 = bl > BAL, m2 = tr > BAL, m3 = br > BAL;
            b = (m0 | m1 | m2 | m3) && !(m0 & m1 & m2 & m3);
        }
        rw = b ? 1 : 0;
        if (((fi | fj) & 1) == 0)
            cal = FIRST ? true : (sCalP[(ip - pOi) * HWF + (jp - pOj)] != 0);
    }
    sRaw[c] = rw; sCfA[c] = 0; sCfB[c] = 0;

    if (__syncthreads_or(rw)) {
        // boundary = any3x3(raw) & ~calc; seed conflicts; occ select
        u8 cf = 0;
        if (li >= 1 && li < HWF - 1 && lj >= 1 && lj < HWF - 1 && inG) {
            bool b = false;
            #pragma unroll
            for (int di = -1; di <= 1; ++di)
                #pragma unroll
                for (int dj = -1; dj <= 1; ++dj)
                    if (sRaw[(li + di) * HWF + (lj + dj)]) b = true;
            b = b && !cal;
            cf = (b && (occ - BAL) * (qv - BAL) < 0.0f) ? 1 : 0;
            if (b) { occ = qv; cal = true; }
            sCfA[c] = cf;
        }
        int haveCf = __syncthreads_or((int)cf);

        #pragma unroll
        for (int it = 0; it < 3; ++it) {
            if (!haveCf) break;
            const u8* cin = (it & 1) ? sCfB : sCfA;
            u8* cout      = (it & 1) ? sCfA : sCfB;
            int lo = 2 + it, hi = HWF - 2 - it;
            u8 nc = 0;
            if (li >= lo && li < hi && lj >= lo && lj < hi && inG) {
                bool any = false;
                #pragma unroll
                for (int di = -1; di <= 1; ++di)
                    #pragma unroll
                    for (int dj = -1; dj <= 1; ++dj)
                        if (cin[(li + di) * HWF + (lj + dj)]) any = true;
                bool cand = any && !cal;
                nc = (cand && (occ - BAL) * (qv - BAL) < 0.0f) ? 1 : 0;
                if (cand) { occ = qv; cal = true; }
                cout[c] = nc;
            }
            haveCf = __syncthreads_or((int)nc);
        }
    }
    occR = occ; calR = cal;
}

// ---- ALL 4 refinement levels, one block per 16x16 output tile ----
// Origins: o4=16b-4, o3=8b-6, o2=4b-7, o1=2b-8; parent reads of each level
// land in [4,17] of the previous window, inside its exact core [4,20).
__global__ __launch_bounds__(NTF) void levels_fused(
    const float* __restrict__ q4, const float* __restrict__ q257,
    float* __restrict__ out)
{
    __shared__ float sOcc[NTF];
    __shared__ u8 sCal[NTF], sRaw[NTF], sCfA[NTF], sCfB[NTF];
    const int bi = blockIdx.x / 33, bj = blockIdx.x - bi * 33;
    const int c = threadIdx.x;
    const int li = c / HWF, lj = c - li * HWF;
    float occ; bool cal;

    // L1: R=65, q = q257 stride 4, parents = 33-grid from q257 (stride 8)
    run_level<true>(c, li, lj, 2 * bi - 8, 2 * bj - 8, 65,
                    q257, 257, 4, q257, 0, 0,
                    sOcc, sCal, sRaw, sCfA, sCfB, occ, cal);
    sOcc[c] = occ; sCal[c] = cal ? 1 : 0;
    __syncthreads();
    // L2: R=129, q = q257 stride 2, parents = L1 patch (origin 2b-8)
    run_level<false>(c, li, lj, 4 * bi - 7, 4 * bj - 7, 129,
                     q257, 257, 2, q257, 2 * bi - 8, 2 * bj - 8,
                     sOcc, sCal, sRaw, sCfA, sCfB, occ, cal);
    sOcc[c] = occ; sCal[c] = cal ? 1 : 0;
    __syncthreads();
    // L3: R=257, q = q257 stride 1 (dense rows), parents = L2 patch (origin 4b-7)
    run_level<false>(c, li, lj, 8 * bi - 6, 8 * bj - 6, 257,
                     q257, 257, 1, q257, 4 * bi - 7, 4 * bj - 7,
                     sOcc, sCal, sRaw, sCfA, sCfB, occ, cal);
    sOcc[c] = occ; sCal[c] = cal ? 1 : 0;
    __syncthreads();
    // L4: R=513, q = q4 stride 1, parents = L3 patch (origin 8b-6)
    run_level<false>(c, li, lj, 16 * bi - 4, 16 * bj - 4, 513,
                     q4, 513, 1, q257, 8 * bi - 6, 8 * bj - 6,
                     sOcc, sCal, sRaw, sCfA, sCfB, occ, cal);

    // write the exact 16x16 core
    const int fi = 16 * bi - 4 + li, fj = 16 * bj - 4 + lj;
    if (li >= 4 && li < 20 && lj >= 4 && lj < 20 &&
        fi < 513 && fj < 513)
        out[fi * 513 + fj] = occ;
}

extern "C" void kernel_launch(void* const* d_in, const int* in_sizes, int n_in,
                              void* d_out, int out_size, void* d_ws, size_t ws_size,
                              hipStream_t stream) {
    const float* W1   = (const float*)d_in[0];
    const float* b1   = (const float*)d_in[1];
    const float* W2   = (const float*)d_in[2];
    const float* b2   = (const float*)d_in[3];
    const float* W3   = (const float*)d_in[4];
    const float* b3   = (const float*)d_in[5];
    const float* bmin = (const float*)d_in[6];
    const float* bmax = (const float*)d_in[7];

    const int N513 = 513 * 513, N257 = 257 * 257;
    float* q4   = (float*)d_ws;
    float* q257 = q4 + N513;
    float* out  = (float*)d_out;

    eval_q4<<<(N513 + TM - 1) / TM, 256, 0, stream>>>(
        W1, b1, W2, b2, W3, b3, bmin, bmax, q4, q257);

    levels_fused<<<33 * 33, NTF, 0, stream>>>(q4, q257, out);
}

// Round 18
// 46.893 us; speedup vs baseline: 5.4942x; 5.4942x over previous
//
#include <hip/hip_runtime.h>

typedef unsigned char u8;
typedef float f32x4 __attribute__((ext_vector_type(4)));
typedef _Float16 f16x8 __attribute__((ext_vector_type(8)));

#define DIM 128
#define TM  128   // eval: points per block (4 waves x 32 points) -- STRAIGHT-LINE
                  // (r17 lesson: any runtime loop around the MFMA block spills
                  //  acc/bh to scratch -> 700MB of HBM traffic. Never loop it.)

__device__ __forceinline__ float fast_tanh(float x) {
    // tanh(x) = 1 - 2/(exp2(2x*log2e)+1); exact +-1 saturation via inf->0
    float e = __builtin_amdgcn_exp2f(x * 2.885390081777927f);
    return 1.0f - 2.0f * __builtin_amdgcn_rcpf(e + 1.0f);
}
__device__ __forceinline__ float fast_sigmoid(float x) {
    float e = __builtin_amdgcn_exp2f(x * -1.4426950408889634f);
    return __builtin_amdgcn_rcpf(1.0f + e);
}

// ---- dense MLP eval of the 513x513 grid; epilogue also writes the 257 shadow ----
// (coarser grids are exact subsets: u=(j*2^s)/512 == j/(R_l-1), bit-identical)
__global__ __launch_bounds__(256, 4) void eval_q4(
    const float* __restrict__ W1, const float* __restrict__ b1,
    const float* __restrict__ W2, const float* __restrict__ b2,
    const float* __restrict__ W3, const float* __restrict__ b3,
    const float* __restrict__ bmin, const float* __restrict__ bmax,
    float* __restrict__ q4, float* __restrict__ q257)
{
    __shared__ __align__(16) _Float16 sW2T[DIM * DIM];   // 32 KB

    const int R = 513;
    const int N = R * R;                 // 263169
    const int tid = threadIdx.x;
    const int m0 = blockIdx.x * TM;

    #pragma unroll
    for (int s = 0; s < 8; ++s) {
        int chunk = s * 256 + tid;       // 0..2047
        int n = chunk & 127, ko = chunk >> 7;
        f16x8 v;
        #pragma unroll
        for (int qq = 0; qq < 8; ++qq)
            v[qq] = (_Float16)W2[(ko * 8 + qq) * DIM + n];   // coalesced over n
        int slot = ko ^ (n & 15);
        *(f16x8*)&sW2T[n * DIM + slot * 8] = v;
    }

    const int w = tid >> 6, lane = tid & 63;
    const int l15 = lane & 15, lg = lane >> 4;

    const float inv = 1.0f / 512.0f;     // exact
    const float bx0 = bmin[0], by0 = bmin[1];
    const float sx = bmax[0] - bx0, sy = bmax[1] - by0;
    float xs[2], ys[2];
    #pragma unroll
    for (int mf = 0; mf < 2; ++mf) {
        int pi = m0 + w * 32 + mf * 16 + l15;
        int pg = (pi < N) ? pi : N - 1;
        int gi = pg / R, gj = pg - gi * R;
        xs[mf] = bx0 + (float)gj * inv * sx;
        ys[mf] = by0 + (float)gi * inv * sy;
    }

    // acc init = b2[col]
    f32x4 acc[2][8];
    #pragma unroll
    for (int nf = 0; nf < 8; ++nf) {
        float b2v = b2[nf * 16 + l15];
        acc[0][nf] = (f32x4)(b2v);
        acc[1][nf] = (f32x4)(b2v);
    }

    __syncthreads();

    #pragma unroll
    for (int kf = 0; kf < 4; ++kf) {
        const int kbase = kf * 32 + lg * 8;
        f16x8 bh[8];
        #pragma unroll
        for (int nf = 0; nf < 8; ++nf) {
            int c = nf * 16 + l15;
            int slot = (kf * 4 + lg) ^ l15;   // matches write swizzle (c&15==l15)
            bh[nf] = *(const f16x8*)&sW2T[c * DIM + slot * 8];
        }
        f32x4 wxa = *(const f32x4*)&W1[kbase];
        f32x4 wxb = *(const f32x4*)&W1[kbase + 4];
        f32x4 wya = *(const f32x4*)&W1[DIM + kbase];
        f32x4 wyb = *(const f32x4*)&W1[DIM + kbase + 4];
        f32x4 b1a = *(const f32x4*)&b1[kbase];
        f32x4 b1b = *(const f32x4*)&b1[kbase + 4];
        f16x8 ah[2];
        #pragma unroll
        for (int mf = 0; mf < 2; ++mf) {
            float x = xs[mf], y = ys[mf];
            #pragma unroll
            for (int qq = 0; qq < 4; ++qq)
                ah[mf][qq] = (_Float16)fast_tanh(fmaf(x, wxa[qq], fmaf(y, wya[qq], b1a[qq])));
            #pragma unroll
            for (int qq = 0; qq < 4; ++qq)
                ah[mf][4 + qq] = (_Float16)fast_tanh(fmaf(x, wxb[qq], fmaf(y, wyb[qq], b1b[qq])));
        }
        #pragma unroll
        for (int nf = 0; nf < 8; ++nf)
            #pragma unroll
            for (int mf = 0; mf < 2; ++mf)
                acc[mf][nf] = __builtin_amdgcn_mfma_f32_16x16x32_f16(ah[mf], bh[nf], acc[mf][nf], 0, 0, 0);
    }

    // epilogue; C/D: row = w*32+mf*16+lg*4+rg, col = nf*16+l15
    float rs[2][4] = {{0,0,0,0},{0,0,0,0}};
    #pragma unroll
    for (int nf = 0; nf < 8; ++nf) {
        float w3v = W3[nf * 16 + l15];
        #pragma unroll
        for (int mf = 0; mf < 2; ++mf)
            #pragma unroll
            for (int rg = 0; rg < 4; ++rg)
                rs[mf][rg] += fast_tanh(acc[mf][nf][rg]) * w3v;
    }
    #pragma unroll
    for (int mf = 0; mf < 2; ++mf)
        #pragma unroll
        for (int rg = 0; rg < 4; ++rg) {
            float v = rs[mf][rg];
            v += __shfl_xor(v, 1);
            v += __shfl_xor(v, 2);
            v += __shfl_xor(v, 4);
            v += __shfl_xor(v, 8);
            rs[mf][rg] = v;
        }
    if (l15 == 0) {
        float b3v = b3[0];
        #pragma unroll
        for (int mf = 0; mf < 2; ++mf)
            #pragma unroll
            for (int rg = 0; rg < 4; ++rg) {
                int po = m0 + w * 32 + mf * 16 + lg * 4 + rg;
                if (po < N) {
                    float val = fast_sigmoid(rs[mf][rg] + b3v);
                    q4[po] = val;
                    int gi = po / R, gj = po - gi * R;
                    if (((gi | gj) & 1) == 0)
                        q257[(gi >> 1) * 257 + (gj >> 1)] = val;  // bit-identical shadow
                }
            }
    }
}

// ---- one refinement level on a 24x24 window, one thread per cell ----
// Window core [4,20) is exact (influence radius of boundary+3 conflict iters
// is 4). Parents come from q257 (FIRST: 33-grid, stride 8) or the previous
// level's LDS patch; q comes from (qbuf,qpitch) at stride qs.
#define HWF 24
#define NTF 576
template<bool FIRST>
__device__ __forceinline__ void run_level(
    int c, int li, int lj, int oi0, int oj0, int R,
    const float* __restrict__ qbuf, int qpitch, int qs,
    const float* __restrict__ q257, int pOi, int pOj,
    const float* sOccP, const u8* sCalP,
    u8* sRaw, u8* sCfA, u8* sCfB,
    float& occR, bool& calR)
{
    const float BAL = 0.5f;
    const int fi = oi0 + li, fj = oj0 + lj;
    const bool inG = (fi >= 0 && fi < R && fj >= 0 && fj < R);
    float occ = 0.5f, qv = 0.5f;
    u8 rw = 0; bool cal = false;
    if (inG) qv = qbuf[(fi * qs) * qpitch + fj * qs];   // issued early, used late
    if (inG) {
        int ip = fi >> 1, jp = fj >> 1;
        int oi = fi & 1, oj = fj & 1;
        float tl = FIRST ? q257[(ip * 8) * 257 + jp * 8]
                         : sOccP[(ip - pOi) * HWF + (jp - pOj)];
        bool b;
        if (!oi && !oj) { occ = tl; b = false; }
        else if (oi && !oj) {
            float bl = FIRST ? q257[((ip + 1) * 8) * 257 + jp * 8]
                             : sOccP[(ip + 1 - pOi) * HWF + (jp - pOj)];
            occ = 0.5f * (tl + bl);
            b = (tl > BAL) != (bl > BAL);
        } else if (!oi && oj) {
            float tr = FIRST ? q257[(ip * 8) * 257 + (jp + 1) * 8]
                             : sOccP[(ip - pOi) * HWF + (jp + 1 - pOj)];
            occ = 0.5f * (tl + tr);
            b = (tl > BAL) != (tr > BAL);
        } else {
            float bl = FIRST ? q257[((ip + 1) * 8) * 257 + jp * 8]
                             : sOccP[(ip + 1 - pOi) * HWF + (jp - pOj)];
            float tr = FIRST ? q257[(ip * 8) * 257 + (jp + 1) * 8]
                             : sOccP[(ip - pOi) * HWF + (jp + 1 - pOj)];
            float br = FIRST ? q257[((ip + 1) * 8) * 257 + (jp + 1) * 8]
                             : sOccP[(ip + 1 - pOi) * HWF + (jp + 1 - pOj)];
            occ = 0.5f * (0.5f * (tl + bl) + 0.5f * (tr + br));  // exact _up2 order
            bool m0 = tl > BAL, m1 = bl > BAL, m2 = tr > BAL, m3 = br > BAL;
            b = (m0 | m1 | m2 | m3) && !(m0 & m1 & m2 & m3);
        }
        rw = b ? 1 : 0;
        if (((fi | fj) & 1) == 0)
            cal = FIRST ? true : (sCalP[(ip - pOi) * HWF + (jp - pOj)] != 0);
    }
    sRaw[c] = rw; sCfA[c] = 0; sCfB[c] = 0;

    if (__syncthreads_or(rw)) {
        // boundary = any3x3(raw) & ~calc; seed conflicts; occ select
        u8 cf = 0;
        if (li >= 1 && li < HWF - 1 && lj >= 1 && lj < HWF - 1 && inG) {
            bool b = false;
            #pragma unroll
            for (int di = -1; di <= 1; ++di)
                #pragma unroll
                for (int dj = -1; dj <= 1; ++dj)
                    if (sRaw[(li + di) * HWF + (lj + dj)]) b = true;
            b = b && !cal;
            cf = (b && (occ - BAL) * (qv - BAL) < 0.0f) ? 1 : 0;
            if (b) { occ = qv; cal = true; }
            sCfA[c] = cf;
        }
        int haveCf = __syncthreads_or((int)cf);

        #pragma unroll
        for (int it = 0; it < 3; ++it) {
            if (!haveCf) break;
            const u8* cin = (it & 1) ? sCfB : sCfA;
            u8* cout      = (it & 1) ? sCfA : sCfB;
            int lo = 2 + it, hi = HWF - 2 - it;
            u8 nc = 0;
            if (li >= lo && li < hi && lj >= lo && lj < hi && inG) {
                bool any = false;
                #pragma unroll
                for (int di = -1; di <= 1; ++di)
                    #pragma unroll
                    for (int dj = -1; dj <= 1; ++dj)
                        if (cin[(li + di) * HWF + (lj + dj)]) any = true;
                bool cand = any && !cal;
                nc = (cand && (occ - BAL) * (qv - BAL) < 0.0f) ? 1 : 0;
                if (cand) { occ = qv; cal = true; }
                cout[c] = nc;
            }
            haveCf = __syncthreads_or((int)nc);
        }
    }
    occR = occ; calR = cal;
}

// ---- ALL 4 refinement levels, one block per 16x16 output tile ----
// Origins: o4=16b-4, o3=8b-6, o2=4b-7, o1=2b-8; parent reads of each level
// land in [4,17] of the previous window, inside its exact core [4,20).
__global__ __launch_bounds__(NTF) void levels_fused(
    const float* __restrict__ q4, const float* __restrict__ q257,
    float* __restrict__ out)
{
    __shared__ float sOcc[NTF];
    __shared__ u8 sCal[NTF], sRaw[NTF], sCfA[NTF], sCfB[NTF];
    const int bi = blockIdx.x / 33, bj = blockIdx.x - bi * 33;
    const int c = threadIdx.x;
    const int li = c / HWF, lj = c - li * HWF;
    float occ; bool cal;

    // L1: R=65, q = q257 stride 4, parents = 33-grid from q257 (stride 8)
    run_level<true>(c, li, lj, 2 * bi - 8, 2 * bj - 8, 65,
                    q257, 257, 4, q257, 0, 0,
                    sOcc, sCal, sRaw, sCfA, sCfB, occ, cal);
    sOcc[c] = occ; sCal[c] = cal ? 1 : 0;
    __syncthreads();
    // L2: R=129, q = q257 stride 2, parents = L1 patch (origin 2b-8)
    run_level<false>(c, li, lj, 4 * bi - 7, 4 * bj - 7, 129,
                     q257, 257, 2, q257, 2 * bi - 8, 2 * bj - 8,
                     sOcc, sCal, sRaw, sCfA, sCfB, occ, cal);
    sOcc[c] = occ; sCal[c] = cal ? 1 : 0;
    __syncthreads();
    // L3: R=257, q = q257 stride 1 (dense rows), parents = L2 patch (origin 4b-7)
    run_level<false>(c, li, lj, 8 * bi - 6, 8 * bj - 6, 257,
                     q257, 257, 1, q257, 4 * bi - 7, 4 * bj - 7,
                     sOcc, sCal, sRaw, sCfA, sCfB, occ, cal);
    sOcc[c] = occ; sCal[c] = cal ? 1 : 0;
    __syncthreads();
    // L4: R=513, q = q4 stride 1, parents = L3 patch (origin 8b-6)
    run_level<false>(c, li, lj, 16 * bi - 4, 16 * bj - 4, 513,
                     q4, 513, 1, q257, 8 * bi - 6, 8 * bj - 6,
                     sOcc, sCal, sRaw, sCfA, sCfB, occ, cal);

    // write the exact 16x16 core
    const int fi = 16 * bi - 4 + li, fj = 16 * bj - 4 + lj;
    if (li >= 4 && li < 20 && lj >= 4 && lj < 20 &&
        fi < 513 && fj < 513)
        out[fi * 513 + fj] = occ;
}

extern "C" void kernel_launch(void* const* d_in, const int* in_sizes, int n_in,
                              void* d_out, int out_size, void* d_ws, size_t ws_size,
                              hipStream_t stream) {
    const float* W1   = (const float*)d_in[0];
    const float* b1   = (const float*)d_in[1];
    const float* W2   = (const float*)d_in[2];
    const float* b2   = (const float*)d_in[3];
    const float* W3   = (const float*)d_in[4];
    const float* b3   = (const float*)d_in[5];
    const float* bmin = (const float*)d_in[6];
    const float* bmax = (const float*)d_in[7];

    const int N513 = 513 * 513;
    float* q4   = (float*)d_ws;
    float* q257 = q4 + N513;
    float* out  = (float*)d_out;

    eval_q4<<<(N513 + TM - 1) / TM, 256, 0, stream>>>(
        W1, b1, W2, b2, W3, b3, bmin, bmax, q4, q257);

    levels_fused<<<33 * 33, NTF, 0, stream>>>(q4, q257, out);
}

// Round 19
// 45.974 us; speedup vs baseline: 5.6040x; 1.0200x over previous
//
#include <hip/hip_runtime.h>

typedef unsigned char u8;
typedef float f32x4 __attribute__((ext_vector_type(4)));
typedef _Float16 f16x8 __attribute__((ext_vector_type(8)));

#define DIM 128
#define TM  128
// r17 lesson: NEVER wrap the MFMA block (acc/bh live state) in a runtime
// loop -- the compiler demotes the arrays to scratch (~1.4KB/thread of HBM
// traffic). Every mlp_wave call below is straight-line from kernel entry.

__device__ __forceinline__ float fast_tanh(float x) {
    // tanh(x) = 1 - 2/(exp2(2x*log2e)+1); exact +-1 saturation via inf->0
    float e = __builtin_amdgcn_exp2f(x * 2.885390081777927f);
    return 1.0f - 2.0f * __builtin_amdgcn_rcpf(e + 1.0f);
}
__device__ __forceinline__ float fast_sigmoid(float x) {
    float e = __builtin_amdgcn_exp2f(x * -1.4426950408889634f);
    return __builtin_amdgcn_rcpf(1.0f + e);
}

// stage W2^T (fp16, XOR-swizzled 16B chunks) into LDS
template<int NT>
__device__ __forceinline__ void stage_w2(const float* __restrict__ W2,
                                         _Float16* sW2T, int tid) {
    #pragma unroll
    for (int s = 0; s < 2048 / NT; ++s) {
        int chunk = s * NT + tid;        // 0..2047
        int n = chunk & 127, ko = chunk >> 7;
        f16x8 v;
        #pragma unroll
        for (int qq = 0; qq < 8; ++qq)
            v[qq] = (_Float16)W2[(ko * 8 + qq) * DIM + n];   // coalesced over n
        int slot = ko ^ (n & 15);
        *(f16x8*)&sW2T[n * DIM + slot * 8] = v;
    }
}

// one wave: 32 points (2 A-frags) x 128 dims; b2 folded into acc init.
// rs[mf][rg] = sum_c tanh(h2)*W3, lane-reduced (valid on all lanes).
// C/D: point-row = mf*16 + lg*4 + rg.
__device__ __forceinline__ void mlp_wave(
    const float xs[2], const float ys[2], const _Float16* sW2T,
    const float* __restrict__ W1, const float* __restrict__ b1,
    const float* __restrict__ b2, const float* __restrict__ W3,
    int lg, int l15, float rs[2][4])
{
    f32x4 acc[2][8];
    #pragma unroll
    for (int nf = 0; nf < 8; ++nf) {
        float b2v = b2[nf * 16 + l15];
        acc[0][nf] = (f32x4)(b2v);
        acc[1][nf] = (f32x4)(b2v);
    }
    #pragma unroll
    for (int kf = 0; kf < 4; ++kf) {
        const int kbase = kf * 32 + lg * 8;
        f16x8 bh[8];
        #pragma unroll
        for (int nf = 0; nf < 8; ++nf) {
            int cc = nf * 16 + l15;
            int slot = (kf * 4 + lg) ^ l15;   // matches stage_w2 swizzle
            bh[nf] = *(const f16x8*)&sW2T[cc * DIM + slot * 8];
        }
        f32x4 wxa = *(const f32x4*)&W1[kbase];
        f32x4 wxb = *(const f32x4*)&W1[kbase + 4];
        f32x4 wya = *(const f32x4*)&W1[DIM + kbase];
        f32x4 wyb = *(const f32x4*)&W1[DIM + kbase + 4];
        f32x4 b1a = *(const f32x4*)&b1[kbase];
        f32x4 b1b = *(const f32x4*)&b1[kbase + 4];
        f16x8 ah[2];
        #pragma unroll
        for (int mf = 0; mf < 2; ++mf) {
            float x = xs[mf], y = ys[mf];
            #pragma unroll
            for (int qq = 0; qq < 4; ++qq)
                ah[mf][qq] = (_Float16)fast_tanh(fmaf(x, wxa[qq], fmaf(y, wya[qq], b1a[qq])));
            #pragma unroll
            for (int qq = 0; qq < 4; ++qq)
                ah[mf][4 + qq] = (_Float16)fast_tanh(fmaf(x, wxb[qq], fmaf(y, wyb[qq], b1b[qq])));
        }
        #pragma unroll
        for (int nf = 0; nf < 8; ++nf)
            #pragma unroll
            for (int mf = 0; mf < 2; ++mf)
                acc[mf][nf] = __builtin_amdgcn_mfma_f32_16x16x32_f16(ah[mf], bh[nf], acc[mf][nf], 0, 0, 0);
    }
    #pragma unroll
    for (int mf = 0; mf < 2; ++mf)
        #pragma unroll
        for (int rg = 0; rg < 4; ++rg) rs[mf][rg] = 0.0f;
    #pragma unroll
    for (int nf = 0; nf < 8; ++nf) {
        float w3v = W3[nf * 16 + l15];
        #pragma unroll
        for (int mf = 0; mf < 2; ++mf)
            #pragma unroll
            for (int rg = 0; rg < 4; ++rg)
                rs[mf][rg] += fast_tanh(acc[mf][nf][rg]) * w3v;
    }
    #pragma unroll
    for (int mf = 0; mf < 2; ++mf)
        #pragma unroll
        for (int rg = 0; rg < 4; ++rg) {
            float v = rs[mf][rg];
            v += __shfl_xor(v, 1);
            v += __shfl_xor(v, 2);
            v += __shfl_xor(v, 4);
            v += __shfl_xor(v, 8);
            rs[mf][rg] = v;
        }
}

// ---- dense MLP eval of an RxR grid (R-1 power of two); straight-line ----
__global__ __launch_bounds__(256, 4) void eval_grid(
    const float* __restrict__ W1, const float* __restrict__ b1,
    const float* __restrict__ W2, const float* __restrict__ b2,
    const float* __restrict__ W3, const float* __restrict__ b3,
    const float* __restrict__ bmin, const float* __restrict__ bmax,
    float* __restrict__ out, int R)
{
    __shared__ __align__(16) _Float16 sW2T[DIM * DIM];   // 32 KB
    const int N = R * R;
    const int tid = threadIdx.x;
    const int m0 = blockIdx.x * TM;
    stage_w2<256>(W2, sW2T, tid);

    const int w = tid >> 6, lane = tid & 63;
    const int l15 = lane & 15, lg = lane >> 4;

    const float inv = 1.0f / (float)(R - 1);   // power-of-two -> exact
    const float bx0 = bmin[0], by0 = bmin[1];
    const float sx = bmax[0] - bx0, sy = bmax[1] - by0;
    float xs[2], ys[2];
    #pragma unroll
    for (int mf = 0; mf < 2; ++mf) {
        int pi = m0 + w * 32 + mf * 16 + l15;
        int pg = (pi < N) ? pi : N - 1;
        int gi = pg / R, gj = pg - gi * R;
        xs[mf] = bx0 + (float)gj * inv * sx;
        ys[mf] = by0 + (float)gi * inv * sy;
    }
    __syncthreads();

    float rs[2][4];
    mlp_wave(xs, ys, sW2T, W1, b1, b2, W3, lg, l15, rs);
    if (l15 == 0) {
        float b3v = b3[0];
        #pragma unroll
        for (int mf = 0; mf < 2; ++mf)
            #pragma unroll
            for (int rg = 0; rg < 4; ++rg) {
                int po = m0 + w * 32 + mf * 16 + lg * 4 + rg;
                if (po < N) out[po] = fast_sigmoid(rs[mf][rg] + b3v);
            }
    }
}

// ---- masked fine eval of the 513 grid: one 16x16 tile per block, 512 thr ----
// Exit unless raw4 (from refined occ257) exists in the +-4-expanded box --
// superset of all q-reads of level 4. 8 waves x 32 pts = 256 pts, ONE
// straight-line mlp_wave call (no loop -> no scratch spill).
__global__ __launch_bounds__(512, 4) void eval_fine(
    const float* __restrict__ W1, const float* __restrict__ b1,
    const float* __restrict__ W2, const float* __restrict__ b2,
    const float* __restrict__ W3, const float* __restrict__ b3,
    const float* __restrict__ bmin, const float* __restrict__ bmax,
    const float* __restrict__ occ3, float* __restrict__ q4)
{
    __shared__ __align__(16) _Float16 sW2T[DIM * DIM];
    const int bi = blockIdx.x / 33, bj = blockIdx.x - bi * 33;
    const int ti0 = bi * 16, tj0 = bj * 16;
    const int tid = threadIdx.x;

    bool need = false;
    for (int s = tid; s < 576; s += 512) {     // no MFMA state live here
        int li = s / 24, lj = s - li * 24;
        int fi = ti0 - 4 + li, fj = tj0 - 4 + lj;
        if (fi >= 0 && fi < 513 && fj >= 0 && fj < 513) {
            int oi = fi & 1, oj = fj & 1;
            if (oi | oj) {
                int ip = fi >> 1, jp = fj >> 1;
                bool m0 = occ3[ip * 257 + jp] > 0.5f;
                bool b;
                if (oi && !oj)      b = m0 != (occ3[(ip + 1) * 257 + jp] > 0.5f);
                else if (!oi && oj) b = m0 != (occ3[ip * 257 + jp + 1] > 0.5f);
                else {
                    bool m1 = occ3[(ip + 1) * 257 + jp] > 0.5f;
                    bool m2 = occ3[ip * 257 + jp + 1] > 0.5f;
                    bool m3 = occ3[(ip + 1) * 257 + jp + 1] > 0.5f;
                    b = (m0 | m1 | m2 | m3) && !(m0 & m1 & m2 & m3);
                }
                need |= b;
            }
        }
    }
    if (!__syncthreads_or(need ? 1 : 0)) return;

    stage_w2<512>(W2, sW2T, tid);
    __syncthreads();

    const int w = tid >> 6, lane = tid & 63;
    const int l15 = lane & 15, lg = lane >> 4;
    const float inv = 1.0f / 512.0f;
    const float bx0 = bmin[0], by0 = bmin[1];
    const float sx = bmax[0] - bx0, sy = bmax[1] - by0;

    float xs[2], ys[2];
    #pragma unroll
    for (int mf = 0; mf < 2; ++mf) {
        int p = w * 32 + mf * 16 + l15;        // 0..255 within tile
        int gi = ti0 + (p >> 4), gj = tj0 + (p & 15);
        if (gi > 512) gi = 512;
        if (gj > 512) gj = 512;
        xs[mf] = bx0 + (float)gj * inv * sx;
        ys[mf] = by0 + (float)gi * inv * sy;
    }
    float rs[2][4];
    mlp_wave(xs, ys, sW2T, W1, b1, b2, W3, lg, l15, rs);
    if (l15 == 0) {
        float b3v = b3[0];
        #pragma unroll
        for (int mf = 0; mf < 2; ++mf)
            #pragma unroll
            for (int rg = 0; rg < 4; ++rg) {
                int p = w * 32 + mf * 16 + lg * 4 + rg;
                int gi = ti0 + (p >> 4), gj = tj0 + (p & 15);
                if (gi < 513 && gj < 513)
                    q4[gi * 513 + gj] = fast_sigmoid(rs[mf][rg] + b3v);
            }
    }
}

// ---- one refinement level on a 24x24 window, one thread per cell ----
#define HWF 24
#define NTF 576
template<bool FIRST>
__device__ __forceinline__ void run_level(
    int c, int li, int lj, int oi0, int oj0, int R,
    const float* __restrict__ qbuf, int qpitch, int qs,
    const float* __restrict__ q257, int pOi, int pOj,
    const float* sOccP, const u8* sCalP,
    u8* sRaw, u8* sCfA, u8* sCfB,
    float& occR, bool& calR)
{
    const float BAL = 0.5f;
    const int fi = oi0 + li, fj = oj0 + lj;
    const bool inG = (fi >= 0 && fi < R && fj >= 0 && fj < R);
    float occ = 0.5f, qv = 0.5f;
    u8 rw = 0; bool cal = false;
    if (inG) qv = qbuf[(fi * qs) * qpitch + fj * qs];   // issued early, used late
    if (inG) {
        int ip = fi >> 1, jp = fj >> 1;
        int oi = fi & 1, oj = fj & 1;
        float tl = FIRST ? q257[(ip * 8) * 257 + jp * 8]
                         : sOccP[(ip - pOi) * HWF + (jp - pOj)];
        bool b;
        if (!oi && !oj) { occ = tl; b = false; }
        else if (oi && !oj) {
            float bl = FIRST ? q257[((ip + 1) * 8) * 257 + jp * 8]
                             : sOccP[(ip + 1 - pOi) * HWF + (jp - pOj)];
            occ = 0.5f * (tl + bl);
            b = (tl > BAL) != (bl > BAL);
        } else if (!oi && oj) {
            float tr = FIRST ? q257[(ip * 8) * 257 + (jp + 1) * 8]
                             : sOccP[(ip - pOi) * HWF + (jp + 1 - pOj)];
            occ = 0.5f * (tl + tr);
            b = (tl > BAL) != (tr > BAL);
        } else {
            float bl = FIRST ? q257[((ip + 1) * 8) * 257 + jp * 8]
                             : sOccP[(ip + 1 - pOi) * HWF + (jp - pOj)];
            float tr = FIRST ? q257[(ip * 8) * 257 + (jp + 1) * 8]
                             : sOccP[(ip - pOi) * HWF + (jp + 1 - pOj)];
            float br = FIRST ? q257[((ip + 1) * 8) * 257 + (jp + 1) * 8]
                             : sOccP[(ip + 1 - pOi) * HWF + (jp + 1 - pOj)];
            occ = 0.5f * (0.5f * (tl + bl) + 0.5f * (tr + br));  // exact _up2 order
            bool m0 = tl > BAL, m1 = bl > BAL, m2 = tr > BAL, m3 = br > BAL;
            b = (m0 | m1 | m2 | m3) && !(m0 & m1 & m2 & m3);
        }
        rw = b ? 1 : 0;
        if (((fi | fj) & 1) == 0)
            cal = FIRST ? true : (sCalP[(ip - pOi) * HWF + (jp - pOj)] != 0);
    }
    sRaw[c] = rw; sCfA[c] = 0; sCfB[c] = 0;

    if (__syncthreads_or(rw)) {
        u8 cf = 0;
        if (li >= 1 && li < HWF - 1 && lj >= 1 && lj < HWF - 1 && inG) {
            bool b = false;
            #pragma unroll
            for (int di = -1; di <= 1; ++di)
                #pragma unroll
                for (int dj = -1; dj <= 1; ++dj)
                    if (sRaw[(li + di) * HWF + (lj + dj)]) b = true;
            b = b && !cal;
            cf = (b && (occ - BAL) * (qv - BAL) < 0.0f) ? 1 : 0;
            if (b) { occ = qv; cal = true; }
            sCfA[c] = cf;
        }
        int haveCf = __syncthreads_or((int)cf);

        #pragma unroll
        for (int it = 0; it < 3; ++it) {
            if (!haveCf) break;
            const u8* cin = (it & 1) ? sCfB : sCfA;
            u8* cout      = (it & 1) ? sCfA : sCfB;
            int lo = 2 + it, hi = HWF - 2 - it;
            u8 nc = 0;
            if (li >= lo && li < hi && lj >= lo && lj < hi && inG) {
                bool any = false;
                #pragma unroll
                for (int di = -1; di <= 1; ++di)
                    #pragma unroll
                    for (int dj = -1; dj <= 1; ++dj)
                        if (cin[(li + di) * HWF + (lj + dj)]) any = true;
                bool cand = any && !cal;
                nc = (cand && (occ - BAL) * (qv - BAL) < 0.0f) ? 1 : 0;
                if (cand) { occ = qv; cal = true; }
                cout[c] = nc;
            }
            haveCf = __syncthreads_or((int)nc);
        }
    }
    occR = occ; calR = cal;
}

// ---- levels 1-3 fused, one block per 16x16 tile of the 257 grid ----
// Origins: o3=16b-4 (257), o2=8b-6 (129), o1=4b-7 (65); each level's parent
// reads land inside the previous window's exact core [4,20).
__global__ __launch_bounds__(NTF) void levels123_fused(
    const float* __restrict__ q257,
    float* __restrict__ occ257, u8* __restrict__ cal257)
{
    __shared__ float sOcc[NTF];
    __shared__ u8 sCal[NTF], sRaw[NTF], sCfA[NTF], sCfB[NTF];
    const int bi = blockIdx.x / 17, bj = blockIdx.x - bi * 17;
    const int c = threadIdx.x;
    const int li = c / HWF, lj = c - li * HWF;
    float occ; bool cal;

    // L1: R=65, q = q257 stride 4, parents = 33-grid from q257 (stride 8)
    run_level<true>(c, li, lj, 4 * bi - 7, 4 * bj - 7, 65,
                    q257, 257, 4, q257, 0, 0,
                    sOcc, sCal, sRaw, sCfA, sCfB, occ, cal);
    sOcc[c] = occ; sCal[c] = cal ? 1 : 0;
    __syncthreads();
    // L2: R=129, q = q257 stride 2, parents = L1 patch (origin 4b-7)
    run_level<false>(c, li, lj, 8 * bi - 6, 8 * bj - 6, 129,
                     q257, 257, 2, q257, 4 * bi - 7, 4 * bj - 7,
                     sOcc, sCal, sRaw, sCfA, sCfB, occ, cal);
    sOcc[c] = occ; sCal[c] = cal ? 1 : 0;
    __syncthreads();
    // L3: R=257, q = q257 stride 1, parents = L2 patch (origin 8b-6)
    run_level<false>(c, li, lj, 16 * bi - 4, 16 * bj - 4, 257,
                     q257, 257, 1, q257, 8 * bi - 6, 8 * bj - 6,
                     sOcc, sCal, sRaw, sCfA, sCfB, occ, cal);

    const int fi = 16 * bi - 4 + li, fj = 16 * bj - 4 + lj;
    if (li >= 4 && li < 20 && lj >= 4 && lj < 20 && fi < 257 && fj < 257) {
        occ257[fi * 257 + fj] = occ;
        cal257[fi * 257 + fj] = cal ? 1 : 0;
    }
}

// ---- level 4 standalone: one block per 16x16 tile of 513, global parents ----
__global__ __launch_bounds__(NTF) void level4_kernel(
    const float* __restrict__ occP, const u8* __restrict__ calcP,
    const float* __restrict__ q4, float* __restrict__ out)
{
    __shared__ u8 sRaw[NTF], sCfA[NTF], sCfB[NTF];
    const int bi = blockIdx.x / 33, bj = blockIdx.x - bi * 33;
    const int fi0 = bi * 16 - 4, fj0 = bj * 16 - 4;
    const int c = threadIdx.x;
    const int li = c / HWF, lj = c - li * HWF;
    const int fi = fi0 + li, fj = fj0 + lj;
    const bool inG = (fi >= 0 && fi < 513 && fj >= 0 && fj < 513);
    const float BAL = 0.5f;

    float occ = 0.5f, qv = 0.5f;
    u8 rw = 0; bool cal = false;
    if (inG) qv = q4[fi * 513 + fj];      // issued early, used late
    if (inG) {
        int ip = fi >> 1, jp = fj >> 1;
        float tl = occP[ip * 257 + jp];
        int oi = fi & 1, oj = fj & 1;
        bool b;
        if (!oi && !oj) { occ = tl; b = false; }
        else if (oi && !oj) {
            float bl = occP[(ip + 1) * 257 + jp];
            occ = 0.5f * (tl + bl);
            b = (tl > BAL) != (bl > BAL);
        } else if (!oi && oj) {
            float tr = occP[ip * 257 + jp + 1];
            occ = 0.5f * (tl + tr);
            b = (tl > BAL) != (tr > BAL);
        } else {
            float bl = occP[(ip + 1) * 257 + jp];
            float tr = occP[ip * 257 + jp + 1];
            float br = occP[(ip + 1) * 257 + jp + 1];
            occ = 0.5f * (0.5f * (tl + bl) + 0.5f * (tr + br));  // exact _up2 order
            bool m0 = tl > BAL, m1 = bl > BAL, m2 = tr > BAL, m3 = br > BAL;
            b = (m0 | m1 | m2 | m3) && !(m0 & m1 & m2 & m3);
        }
        rw = b ? 1 : 0;
        if (((fi | fj) & 1) == 0) cal = calcP[ip * 257 + jp] != 0;
    }
    sRaw[c] = rw; sCfA[c] = 0; sCfB[c] = 0;

    if (__syncthreads_or(rw)) {
        u8 cf = 0;
        if (li >= 1 && li < HWF - 1 && lj >= 1 && lj < HWF - 1 && inG) {
            bool b = false;
            #pragma unroll
            for (int di = -1; di <= 1; ++di)
                #pragma unroll
                for (int dj = -1; dj <= 1; ++dj)
                    if (sRaw[(li + di) * HWF + (lj + dj)]) b = true;
            b = b && !cal;
            cf = (b && (occ - BAL) * (qv - BAL) < 0.0f) ? 1 : 0;
            if (b) { occ = qv; cal = true; }
            sCfA[c] = cf;
        }
        int haveCf = __syncthreads_or((int)cf);

        #pragma unroll
        for (int it = 0; it < 3; ++it) {
            if (!haveCf) break;
            const u8* cin = (it & 1) ? sCfB : sCfA;
            u8* cout      = (it & 1) ? sCfA : sCfB;
            int lo = 2 + it, hi = HWF - 2 - it;
            u8 nc = 0;
            if (li >= lo && li < hi && lj >= lo && lj < hi && inG) {
                bool any = false;
                #pragma unroll
                for (int di = -1; di <= 1; ++di)
                    #pragma unroll
                    for (int dj = -1; dj <= 1; ++dj)
                        if (cin[(li + di) * HWF + (lj + dj)]) any = true;
                bool cand = any && !cal;
                nc = (cand && (occ - BAL) * (qv - BAL) < 0.0f) ? 1 : 0;
                if (cand) { occ = qv; cal = true; }
                cout[c] = nc;
            }
            haveCf = __syncthreads_or((int)nc);
        }
    }

    if (li >= 4 && li < 20 && lj >= 4 && lj < 20 && inG)
        out[fi * 513 + fj] = occ;
}

extern "C" void kernel_launch(void* const* d_in, const int* in_sizes, int n_in,
                              void* d_out, int out_size, void* d_ws, size_t ws_size,
                              hipStream_t stream) {
    const float* W1   = (const float*)d_in[0];
    const float* b1   = (const float*)d_in[1];
    const float* W2   = (const float*)d_in[2];
    const float* b2   = (const float*)d_in[3];
    const float* W3   = (const float*)d_in[4];
    const float* b3   = (const float*)d_in[5];
    const float* bmin = (const float*)d_in[6];
    const float* bmax = (const float*)d_in[7];

    const int N513 = 513 * 513, N257 = 257 * 257;
    float* q257   = (float*)d_ws;
    float* occ257 = q257 + N257;
    float* q4     = occ257 + N257;
    u8*    cal257 = (u8*)(q4 + N513);
    float* out    = (float*)d_out;

    // 1) dense eval at 257 (covers all q-reads of levels 1-3 bit-exactly)
    eval_grid<<<(N257 + TM - 1) / TM, 256, 0, stream>>>(
        W1, b1, W2, b2, W3, b3, bmin, bmax, q257, 257);

    // 2) levels 1-3 fused -> refined occ257 + cal257
    levels123_fused<<<17 * 17, NTF, 0, stream>>>(q257, occ257, cal257);

    // 3) masked fine eval of the 513 grid (only boundary-adjacent tiles)
    eval_fine<<<33 * 33, 512, 0, stream>>>(
        W1, b1, W2, b2, W3, b3, bmin, bmax, occ257, q4);

    // 4) level 4 -> output
    level4_kernel<<<33 * 33, NTF, 0, stream>>>(occ257, cal257, q4, out);
}